// Round 1
// baseline (3832.696 us; speedup 1.0000x reference)
//
#include <hip/hip_runtime.h>
#include <hip/hip_bf16.h>

// MLA prefill: B=2,S=2048,DIM=2048,NH=16,D_NOPE=128,D_ROPE=64,D_V=128,KV_RANK=512
// Round 1: correctness-first pipeline. bf16 MFMA GEMMs (m92/93-level), f32 vector
// flash attention. Later rounds: MFMA attention, global_load_lds staging.

typedef __bf16 bf16x8 __attribute__((ext_vector_type(8)));
typedef float  f32x4  __attribute__((ext_vector_type(4)));
typedef unsigned short us8 __attribute__((ext_vector_type(8)));

#define S_LEN   2048
#define BS_TOT  4096   // B*S
#define NH      16
#define DQK     192
#define DV      128
#define KV_RANK 512

// ---------------- f32 -> bf16 cast ----------------
__global__ void cast_f32_bf16_kernel(const float* __restrict__ src,
                                     __hip_bfloat16* __restrict__ dst, int n) {
  int tid = blockIdx.x * blockDim.x + threadIdx.x;
  int stride = gridDim.x * blockDim.x;
  for (int i = tid * 4; i < n; i += stride * 4) {
    f32x4 v = *(const f32x4*)(src + i);
    dst[i + 0] = __float2bfloat16(v.x);
    dst[i + 1] = __float2bfloat16(v.y);
    dst[i + 2] = __float2bfloat16(v.z);
    dst[i + 3] = __float2bfloat16(v.w);
  }
}

// ---------------- bf16 MFMA GEMM: C[M,N] = A[M,K] @ Bw[N,K]^T ----------------
// 128x128 block tile, BK=32, 4 waves each computing 64x64 via 4x4 MFMA frags.
// M % 128 == 0 and K % 32 == 0 guaranteed by the problem; N may have a tail.
template<int OUT_BF16>
__global__ __launch_bounds__(256) void gemm_bt(const __hip_bfloat16* __restrict__ A,
                                               const __hip_bfloat16* __restrict__ Bw,
                                               void* __restrict__ Cp,
                                               int M, int N, int K) {
  constexpr int BM = 128, BN = 128, BK = 32;
  __shared__ alignas(16) unsigned short As[BM * BK];
  __shared__ alignas(16) unsigned short Bs[BN * BK];
  const int tid  = threadIdx.x;
  const int m0   = blockIdx.y * BM, n0 = blockIdx.x * BN;
  const int w    = tid >> 6, lane = tid & 63;
  const int wm   = (w >> 1) * 64, wn = (w & 1) * 64;
  const int ml   = lane & 15, quad = lane >> 4;
  const int lrow = tid >> 2;          // 0..63
  const int lcol = (tid & 3) * 8;     // 0,8,16,24

  f32x4 acc[4][4];
#pragma unroll
  for (int i = 0; i < 4; i++)
#pragma unroll
    for (int j = 0; j < 4; j++)
#pragma unroll
      for (int e = 0; e < 4; e++) acc[i][j][e] = 0.0f;

  const unsigned short* Ag = (const unsigned short*)A;
  const unsigned short* Bg = (const unsigned short*)Bw;

  for (int k0 = 0; k0 < K; k0 += BK) {
    __syncthreads();
    // A tile (rows always in-bounds)
    *(us8*)&As[lrow * BK + lcol] =
        *(const us8*)&Ag[(size_t)(m0 + lrow) * K + k0 + lcol];
    *(us8*)&As[(lrow + 64) * BK + lcol] =
        *(const us8*)&Ag[(size_t)(m0 + lrow + 64) * K + k0 + lcol];
    // B tile with N-tail zero fill
    int n1 = n0 + lrow, n2 = n0 + lrow + 64;
    us8 bv0, bv1;
#pragma unroll
    for (int z = 0; z < 8; z++) { bv0[z] = 0; bv1[z] = 0; }
    if (n1 < N) bv0 = *(const us8*)&Bg[(size_t)n1 * K + k0 + lcol];
    if (n2 < N) bv1 = *(const us8*)&Bg[(size_t)n2 * K + k0 + lcol];
    *(us8*)&Bs[lrow * BK + lcol] = bv0;
    *(us8*)&Bs[(lrow + 64) * BK + lcol] = bv1;
    __syncthreads();

    bf16x8 af[4], bfr[4];
#pragma unroll
    for (int mi = 0; mi < 4; mi++)
      af[mi] = *(const bf16x8*)&As[(wm + mi * 16 + ml) * BK + quad * 8];
#pragma unroll
    for (int ni = 0; ni < 4; ni++)
      bfr[ni] = *(const bf16x8*)&Bs[(wn + ni * 16 + ml) * BK + quad * 8];
#pragma unroll
    for (int mi = 0; mi < 4; mi++)
#pragma unroll
      for (int ni = 0; ni < 4; ni++)
        acc[mi][ni] = __builtin_amdgcn_mfma_f32_16x16x32_bf16(af[mi], bfr[ni],
                                                              acc[mi][ni], 0, 0, 0);
  }

  // epilogue: D[row=quad*4+j][col=ml]
#pragma unroll
  for (int mi = 0; mi < 4; mi++) {
#pragma unroll
    for (int ni = 0; ni < 4; ni++) {
      int col = n0 + wn + ni * 16 + ml;
      if (col < N) {
#pragma unroll
        for (int j = 0; j < 4; j++) {
          int row = m0 + wm + mi * 16 + quad * 4 + j;
          float v = acc[mi][ni][j];
          if (OUT_BF16)
            ((__hip_bfloat16*)Cp)[(size_t)row * N + col] = __float2bfloat16(v);
          else
            ((float*)Cp)[(size_t)row * N + col] = v;
        }
      }
    }
  }
}

// ---------------- RoPE on q_pe (in place, bf16 q [BS][NH*192]) ----------------
__global__ __launch_bounds__(256) void rope_q_kernel(__hip_bfloat16* __restrict__ q,
                                                     const float* __restrict__ freqs) {
  int si = blockIdx.x;             // 0..BS-1
  int s  = si & (S_LEN - 1);       // position
  int tid = threadIdx.x;
  for (int p = tid; p < NH * 32; p += 256) {
    int h = p >> 5, i = p & 31;
    size_t base = (size_t)si * (NH * DQK) + h * DQK + 128 + 2 * i;
    float c  = freqs[s * 64 + 2 * i];
    float sn = freqs[s * 64 + 2 * i + 1];
    float x0 = __bfloat162float(q[base]);
    float x1 = __bfloat162float(q[base + 1]);
    q[base]     = __float2bfloat16(x0 * c - x1 * sn);
    q[base + 1] = __float2bfloat16(x0 * sn + x1 * c);
  }
}

// -------- RMSNorm(kv latent) -> bf16, RoPE(k_pe) -> f32. kva: [BS][576] f32 -----
__global__ __launch_bounds__(256) void rms_rope_kv_kernel(
    const float* __restrict__ kva, const float* __restrict__ w,
    const float* __restrict__ freqs, __hip_bfloat16* __restrict__ latent,
    float* __restrict__ kpe_out) {
  int si = blockIdx.x;
  int tid = threadIdx.x;
  const float* row = kva + (size_t)si * 576;
  float v0 = row[tid], v1 = row[tid + 256];
  float ss = v0 * v0 + v1 * v1;
#pragma unroll
  for (int off = 1; off < 64; off <<= 1) ss += __shfl_xor(ss, off, 64);
  __shared__ float red[4];
  if ((tid & 63) == 0) red[tid >> 6] = ss;
  __syncthreads();
  float tot = red[0] + red[1] + red[2] + red[3];
  float r = rsqrtf(tot / 512.0f + 1e-6f);
  latent[(size_t)si * 512 + tid]       = __float2bfloat16(v0 * r * w[tid]);
  latent[(size_t)si * 512 + tid + 256] = __float2bfloat16(v1 * r * w[tid + 256]);
  if (tid < 32) {
    int s = si & (S_LEN - 1);
    float c  = freqs[s * 64 + 2 * tid];
    float sn = freqs[s * 64 + 2 * tid + 1];
    float x0 = row[512 + 2 * tid], x1 = row[512 + 2 * tid + 1];
    kpe_out[(size_t)si * 64 + 2 * tid]     = x0 * c - x1 * sn;
    kpe_out[(size_t)si * 64 + 2 * tid + 1] = x0 * sn + x1 * c;
  }
}

// ---------------- causal flash attention (f32 vector, round-1 baseline) --------
// grid (S/16, NH, B), 256 threads. K = [k_nope | k_pe], from kvup/kpe.
__global__ __launch_bounds__(256) void attn_kernel(
    const __hip_bfloat16* __restrict__ qb,    // [BS][NH*192]
    const __hip_bfloat16* __restrict__ kvup,  // [BS][NH*256] (nope|v per head)
    const float* __restrict__ kpe,            // [BS][64]
    __hip_bfloat16* __restrict__ attn_out) {  // [BS][NH*128]
  constexpr int TQ = 16, TK = 32;
  constexpr int QS = 196, KS = 196, VS = 132;  // padded f32 strides
  __shared__ alignas(16) float Qs[TQ * QS];
  __shared__ alignas(16) float Ks[TK * KS];
  __shared__ alignas(16) float Vs[TK * VS];
  __shared__ float Ps[TQ * TK];

  const int qt = blockIdx.x, h = blockIdx.y, b = blockIdx.z;
  const int tid = threadIdx.x;
  const float scale = 0.07216878364870322f;  // 192^-0.5

  // load + scale Q tile
  size_t qbase = ((size_t)(b * S_LEN + qt * TQ)) * (NH * DQK) + h * DQK;
  for (int i = tid; i < TQ * DQK; i += 256) {
    int r = i / DQK, d = i % DQK;
    Qs[r * QS + d] = __bfloat162float(qb[qbase + (size_t)r * (NH * DQK) + d]) * scale;
  }

  const int r   = tid >> 4;       // q row 0..15 (same grouping both phases)
  const int c16 = tid & 15;
  const int q_glob = qt * TQ + r;
  const int dA = c16 * 4, dB = 64 + c16 * 4;   // O dims owned by this thread
  float m_i = -1e30f, l_i = 0.0f;
  float O[8];
#pragma unroll
  for (int j = 0; j < 8; j++) O[j] = 0.0f;

  const int kmax = qt * TQ + TQ;
  for (int kb = 0; kb < kmax; kb += TK) {
    __syncthreads();
    // K tile: nope from kvup, pe from kpe
    for (int i = tid; i < TK * DQK; i += 256) {
      int kr = i / DQK, d = i % DQK;
      size_t rowg = (size_t)(b * S_LEN + kb + kr);
      float v = (d < 128) ? __bfloat162float(kvup[rowg * (NH * 256) + h * 256 + d])
                          : kpe[rowg * 64 + (d - 128)];
      Ks[kr * KS + d] = v;
    }
    for (int i = tid; i < TK * DV; i += 256) {
      int kr = i / DV, d = i % DV;
      size_t rowg = (size_t)(b * S_LEN + kb + kr);
      Vs[kr * VS + d] = __bfloat162float(kvup[rowg * (NH * 256) + h * 256 + 128 + d]);
    }
    __syncthreads();

    // scores: thread computes 2 dots (k = c16, c16+16) for row r
    float s0 = 0.0f, s1 = 0.0f;
    const float* qrow = &Qs[r * QS];
    const float* k0p  = &Ks[c16 * KS];
    const float* k1p  = &Ks[(c16 + 16) * KS];
#pragma unroll 4
    for (int d = 0; d < DQK; d += 4) {
      f32x4 qv = *(const f32x4*)(qrow + d);
      f32x4 a  = *(const f32x4*)(k0p + d);
      f32x4 bv = *(const f32x4*)(k1p + d);
      s0 += qv.x * a.x + qv.y * a.y + qv.z * a.z + qv.w * a.w;
      s1 += qv.x * bv.x + qv.y * bv.y + qv.z * bv.z + qv.w * bv.w;
    }
    if (kb + c16 > q_glob)      s0 = -1e30f;
    if (kb + c16 + 16 > q_glob) s1 = -1e30f;

    // online softmax (row = 16 contiguous lanes of one wave)
    float mx = fmaxf(s0, s1);
#pragma unroll
    for (int off = 1; off < 16; off <<= 1) mx = fmaxf(mx, __shfl_xor(mx, off, 64));
    float m_new = fmaxf(m_i, mx);
    float alpha = __expf(m_i - m_new);
    float p0 = __expf(s0 - m_new), p1 = __expf(s1 - m_new);
    float ps = p0 + p1;
#pragma unroll
    for (int off = 1; off < 16; off <<= 1) ps += __shfl_xor(ps, off, 64);
    l_i = l_i * alpha + ps;
    m_i = m_new;
    Ps[r * TK + c16] = p0;
    Ps[r * TK + c16 + 16] = p1;   // same-wave LDS: in-order, no barrier needed

#pragma unroll
    for (int j = 0; j < 8; j++) O[j] *= alpha;
    for (int kk = 0; kk < TK; kk++) {
      float p = Ps[r * TK + kk];  // broadcast
      f32x4 va = *(const f32x4*)&Vs[kk * VS + dA];
      f32x4 vb = *(const f32x4*)&Vs[kk * VS + dB];
      O[0] += p * va.x; O[1] += p * va.y; O[2] += p * va.z; O[3] += p * va.w;
      O[4] += p * vb.x; O[5] += p * vb.y; O[6] += p * vb.z; O[7] += p * vb.w;
    }
  }

  float inv_l = 1.0f / l_i;
  size_t orow = ((size_t)(b * S_LEN + qt * TQ + r)) * (NH * DV) + h * DV;
#pragma unroll
  for (int j = 0; j < 4; j++) {
    attn_out[orow + dA + j] = __float2bfloat16(O[j] * inv_l);
    attn_out[orow + dB + j] = __float2bfloat16(O[4 + j] * inv_l);
  }
}

// ---------------- launch ----------------
extern "C" void kernel_launch(void* const* d_in, const int* in_sizes, int n_in,
                              void* d_out, int out_size, void* d_ws, size_t ws_size,
                              hipStream_t stream) {
  const float* x     = (const float*)d_in[0];
  const float* freqs = (const float*)d_in[2];
  const float* wq    = (const float*)d_in[4];
  const float* wkva  = (const float*)d_in[5];
  const float* wkvb  = (const float*)d_in[6];
  const float* wo    = (const float*)d_in[7];
  const float* kvnw  = (const float*)d_in[8];
  float* out = (float*)d_out;

  char* ws = (char*)d_ws;
  size_t off = 0;
  auto alloc = [&](size_t bytes) {
    void* p = ws + off;
    off += (bytes + 255) & ~(size_t)255;
    return p;
  };
  __hip_bfloat16* x_bf    = (__hip_bfloat16*)alloc((size_t)BS_TOT * 2048 * 2);
  __hip_bfloat16* wq_bf   = (__hip_bfloat16*)alloc((size_t)3072 * 2048 * 2);
  __hip_bfloat16* wkva_bf = (__hip_bfloat16*)alloc((size_t)576 * 2048 * 2);
  __hip_bfloat16* wkvb_bf = (__hip_bfloat16*)alloc((size_t)4096 * 512 * 2);
  __hip_bfloat16* wo_bf   = (__hip_bfloat16*)alloc((size_t)2048 * 2048 * 2);
  __hip_bfloat16* q_bf    = (__hip_bfloat16*)alloc((size_t)BS_TOT * 3072 * 2);
  float*          kva     = (float*)alloc((size_t)BS_TOT * 576 * 4);
  __hip_bfloat16* latent  = (__hip_bfloat16*)alloc((size_t)BS_TOT * 512 * 2);
  float*          kpe     = (float*)alloc((size_t)BS_TOT * 64 * 4);
  __hip_bfloat16* kvup    = (__hip_bfloat16*)alloc((size_t)BS_TOT * 4096 * 2);
  __hip_bfloat16* attn    = (__hip_bfloat16*)alloc((size_t)BS_TOT * 2048 * 2);

  // casts
  cast_f32_bf16_kernel<<<2048, 256, 0, stream>>>(x, x_bf, BS_TOT * 2048);
  cast_f32_bf16_kernel<<<2048, 256, 0, stream>>>(wq, wq_bf, 3072 * 2048);
  cast_f32_bf16_kernel<<<1024, 256, 0, stream>>>(wkva, wkva_bf, 576 * 2048);
  cast_f32_bf16_kernel<<<1024, 256, 0, stream>>>(wkvb, wkvb_bf, 4096 * 512);
  cast_f32_bf16_kernel<<<2048, 256, 0, stream>>>(wo, wo_bf, 2048 * 2048);

  // q = x @ wq^T  (bf16 out), then rope q_pe
  gemm_bt<1><<<dim3(3072 / 128, BS_TOT / 128), 256, 0, stream>>>(
      x_bf, wq_bf, q_bf, BS_TOT, 3072, 2048);
  rope_q_kernel<<<BS_TOT, 256, 0, stream>>>(q_bf, freqs);

  // kv_a = x @ wkv_a^T (f32 out), then rmsnorm latent + rope k_pe
  gemm_bt<0><<<dim3(5, BS_TOT / 128), 256, 0, stream>>>(
      x_bf, wkva_bf, kva, BS_TOT, 576, 2048);
  rms_rope_kv_kernel<<<BS_TOT, 256, 0, stream>>>(kva, kvnw, freqs, latent, kpe);

  // kv_up = latent @ wkv_b^T (bf16 out): per row [h][nope(128)|v(128)]
  gemm_bt<1><<<dim3(4096 / 128, BS_TOT / 128), 256, 0, stream>>>(
      latent, wkvb_bf, kvup, BS_TOT, 4096, 512);

  // attention
  attn_kernel<<<dim3(S_LEN / 16, NH, 2), 256, 0, stream>>>(q_bf, kvup, kpe, attn);

  // out = attn @ wo^T (f32 out)
  gemm_bt<0><<<dim3(2048 / 128, BS_TOT / 128), 256, 0, stream>>>(
      attn, wo_bf, out, BS_TOT, 2048, 2048);
}

// Round 2
// 783.835 us; speedup vs baseline: 4.8897x; 4.8897x over previous
//
#include <hip/hip_runtime.h>
#include <hip/hip_bf16.h>

// MLA prefill: B=2,S=2048,DIM=2048,NH=16,D_NOPE=128,D_ROPE=64,D_V=128,KV_RANK=512
// R2: MFMA flash attention (S^T=K·Q^T trick for cheap softmax, P via LDS
// round-trip, V staged kr-pair-interleaved). GEMMs unchanged from R1.

typedef __bf16 bf16x8 __attribute__((ext_vector_type(8)));
typedef float  f32x4  __attribute__((ext_vector_type(4)));
typedef unsigned short us8 __attribute__((ext_vector_type(8)));

#define S_LEN   2048
#define BS_TOT  4096   // B*S
#define NH      16
#define DQK     192
#define DV      128
#define KV_RANK 512

__device__ inline unsigned short f2bf(float f) {
  __hip_bfloat16 h = __float2bfloat16(f);
  return *reinterpret_cast<unsigned short*>(&h);
}

// ---------------- f32 -> bf16 cast ----------------
__global__ void cast_f32_bf16_kernel(const float* __restrict__ src,
                                     __hip_bfloat16* __restrict__ dst, int n) {
  int tid = blockIdx.x * blockDim.x + threadIdx.x;
  int stride = gridDim.x * blockDim.x;
  for (int i = tid * 4; i < n; i += stride * 4) {
    f32x4 v = *(const f32x4*)(src + i);
    dst[i + 0] = __float2bfloat16(v.x);
    dst[i + 1] = __float2bfloat16(v.y);
    dst[i + 2] = __float2bfloat16(v.z);
    dst[i + 3] = __float2bfloat16(v.w);
  }
}

// ---------------- bf16 MFMA GEMM: C[M,N] = A[M,K] @ Bw[N,K]^T ----------------
template<int OUT_BF16>
__global__ __launch_bounds__(256) void gemm_bt(const __hip_bfloat16* __restrict__ A,
                                               const __hip_bfloat16* __restrict__ Bw,
                                               void* __restrict__ Cp,
                                               int M, int N, int K) {
  constexpr int BM = 128, BN = 128, BK = 32;
  __shared__ alignas(16) unsigned short As[BM * BK];
  __shared__ alignas(16) unsigned short Bs[BN * BK];
  const int tid  = threadIdx.x;
  const int m0   = blockIdx.y * BM, n0 = blockIdx.x * BN;
  const int w    = tid >> 6, lane = tid & 63;
  const int wm   = (w >> 1) * 64, wn = (w & 1) * 64;
  const int ml   = lane & 15, quad = lane >> 4;
  const int lrow = tid >> 2;
  const int lcol = (tid & 3) * 8;

  f32x4 acc[4][4];
#pragma unroll
  for (int i = 0; i < 4; i++)
#pragma unroll
    for (int j = 0; j < 4; j++)
#pragma unroll
      for (int e = 0; e < 4; e++) acc[i][j][e] = 0.0f;

  const unsigned short* Ag = (const unsigned short*)A;
  const unsigned short* Bg = (const unsigned short*)Bw;

  for (int k0 = 0; k0 < K; k0 += BK) {
    __syncthreads();
    *(us8*)&As[lrow * BK + lcol] =
        *(const us8*)&Ag[(size_t)(m0 + lrow) * K + k0 + lcol];
    *(us8*)&As[(lrow + 64) * BK + lcol] =
        *(const us8*)&Ag[(size_t)(m0 + lrow + 64) * K + k0 + lcol];
    int n1 = n0 + lrow, n2 = n0 + lrow + 64;
    us8 bv0, bv1;
#pragma unroll
    for (int z = 0; z < 8; z++) { bv0[z] = 0; bv1[z] = 0; }
    if (n1 < N) bv0 = *(const us8*)&Bg[(size_t)n1 * K + k0 + lcol];
    if (n2 < N) bv1 = *(const us8*)&Bg[(size_t)n2 * K + k0 + lcol];
    *(us8*)&Bs[lrow * BK + lcol] = bv0;
    *(us8*)&Bs[(lrow + 64) * BK + lcol] = bv1;
    __syncthreads();

    bf16x8 af[4], bfr[4];
#pragma unroll
    for (int mi = 0; mi < 4; mi++)
      af[mi] = *(const bf16x8*)&As[(wm + mi * 16 + ml) * BK + quad * 8];
#pragma unroll
    for (int ni = 0; ni < 4; ni++)
      bfr[ni] = *(const bf16x8*)&Bs[(wn + ni * 16 + ml) * BK + quad * 8];
#pragma unroll
    for (int mi = 0; mi < 4; mi++)
#pragma unroll
      for (int ni = 0; ni < 4; ni++)
        acc[mi][ni] = __builtin_amdgcn_mfma_f32_16x16x32_bf16(af[mi], bfr[ni],
                                                              acc[mi][ni], 0, 0, 0);
  }

#pragma unroll
  for (int mi = 0; mi < 4; mi++) {
#pragma unroll
    for (int ni = 0; ni < 4; ni++) {
      int col = n0 + wn + ni * 16 + ml;
      if (col < N) {
#pragma unroll
        for (int j = 0; j < 4; j++) {
          int row = m0 + wm + mi * 16 + quad * 4 + j;
          float v = acc[mi][ni][j];
          if (OUT_BF16)
            ((__hip_bfloat16*)Cp)[(size_t)row * N + col] = __float2bfloat16(v);
          else
            ((float*)Cp)[(size_t)row * N + col] = v;
        }
      }
    }
  }
}

// ---------------- RoPE on q_pe (in place, bf16 q [BS][NH*192]) ----------------
__global__ __launch_bounds__(256) void rope_q_kernel(__hip_bfloat16* __restrict__ q,
                                                     const float* __restrict__ freqs) {
  int si = blockIdx.x;
  int s  = si & (S_LEN - 1);
  int tid = threadIdx.x;
  for (int p = tid; p < NH * 32; p += 256) {
    int h = p >> 5, i = p & 31;
    size_t base = (size_t)si * (NH * DQK) + h * DQK + 128 + 2 * i;
    float c  = freqs[s * 64 + 2 * i];
    float sn = freqs[s * 64 + 2 * i + 1];
    float x0 = __bfloat162float(q[base]);
    float x1 = __bfloat162float(q[base + 1]);
    q[base]     = __float2bfloat16(x0 * c - x1 * sn);
    q[base + 1] = __float2bfloat16(x0 * sn + x1 * c);
  }
}

// -------- RMSNorm(kv latent) -> bf16, RoPE(k_pe) -> f32 ----------------------
__global__ __launch_bounds__(256) void rms_rope_kv_kernel(
    const float* __restrict__ kva, const float* __restrict__ w,
    const float* __restrict__ freqs, __hip_bfloat16* __restrict__ latent,
    float* __restrict__ kpe_out) {
  int si = blockIdx.x;
  int tid = threadIdx.x;
  const float* row = kva + (size_t)si * 576;
  float v0 = row[tid], v1 = row[tid + 256];
  float ss = v0 * v0 + v1 * v1;
#pragma unroll
  for (int off = 1; off < 64; off <<= 1) ss += __shfl_xor(ss, off, 64);
  __shared__ float red[4];
  if ((tid & 63) == 0) red[tid >> 6] = ss;
  __syncthreads();
  float tot = red[0] + red[1] + red[2] + red[3];
  float r = rsqrtf(tot / 512.0f + 1e-6f);
  latent[(size_t)si * 512 + tid]       = __float2bfloat16(v0 * r * w[tid]);
  latent[(size_t)si * 512 + tid + 256] = __float2bfloat16(v1 * r * w[tid + 256]);
  if (tid < 32) {
    int s = si & (S_LEN - 1);
    float c  = freqs[s * 64 + 2 * tid];
    float sn = freqs[s * 64 + 2 * tid + 1];
    float x0 = row[512 + 2 * tid], x1 = row[512 + 2 * tid + 1];
    kpe_out[(size_t)si * 64 + 2 * tid]     = x0 * c - x1 * sn;
    kpe_out[(size_t)si * 64 + 2 * tid + 1] = x0 * sn + x1 * c;
  }
}

// ---------------- MFMA flash attention ----------------------------------------
// grid (S/64, NH, B), 256 threads (4 waves x 16 q-rows). K-tile = 64.
// S^T = K·Q^T so softmax is lane-local (+2 shfl); P via LDS; V pair-interleaved.
__global__ __launch_bounds__(256) void attn_mfma_kernel(
    const __hip_bfloat16* __restrict__ qb,    // [BS][NH*192]
    const __hip_bfloat16* __restrict__ kvup,  // [BS][NH*256] (nope|v per head)
    const float* __restrict__ kpe,            // [BS][64]
    __hip_bfloat16* __restrict__ attn_out) {  // [BS][NH*128]
  constexpr int KS = 200;  // Ks row stride (elems): 400B = 25x16, 2-way banks
  constexpr int PS = 72;   // Ps row stride: 144B, 16B-aligned
  __shared__ alignas(16) unsigned short Ks[64 * KS];   // 25600 B
  __shared__ alignas(16) unsigned int   Vt2[128 * 33]; // 16896 B  [d][kr/2] pairs
  __shared__ alignas(16) unsigned short Ps[4][16 * PS];// 9216 B

  const int qt = blockIdx.x, h = blockIdx.y, b = blockIdx.z;
  const int tid = threadIdx.x, wave = tid >> 6, lane = tid & 63;
  const int ml = lane & 15, quad = lane >> 4;
  const int qw = qt * 64 + wave * 16;
  const float scale = 0.07216878364870322f;  // 192^-0.5

  // resident Q B-frags: n=ml -> q row qw+ml; k = kc*32 + quad*8 + j
  bf16x8 Qf[6];
  {
    const unsigned short* qrow = (const unsigned short*)qb +
        (size_t)(b * S_LEN + qw + ml) * (NH * DQK) + h * DQK;
#pragma unroll
    for (int kc = 0; kc < 6; kc++)
      Qf[kc] = *(const bf16x8*)(qrow + kc * 32 + quad * 8);
  }

  float m_i = -1e30f, l_i = 0.0f;
  f32x4 O[8];
#pragma unroll
  for (int nt = 0; nt < 8; nt++)
#pragma unroll
    for (int j = 0; j < 4; j++) O[nt][j] = 0.0f;

  unsigned short* myP = Ps[wave];
  const int nkt = qt + 1;
  for (int kt = 0; kt < nkt; kt++) {
    const int kb = kt * 64;
    __syncthreads();
    // ---- stage K: 64 rows x 192 (nope bf16 | rope f32->bf16) ----
    for (int i = tid; i < 64 * 24; i += 256) {
      int r = i / 24, c = i - r * 24;
      size_t grow = (size_t)(b * S_LEN + kb + r);
      us8 val;
      if (c < 16) {
        val = *(const us8*)((const unsigned short*)kvup + grow * (NH * 256) +
                            h * 256 + c * 8);
      } else {
        const float* kp = kpe + grow * 64 + (c - 16) * 8;
#pragma unroll
        for (int z = 0; z < 8; z++) val[z] = f2bf(kp[z]);
      }
      *(us8*)&Ks[r * KS + c * 8] = val;
    }
    // ---- stage V transposed, kr-pair-interleaved: Vt2[d][kr/2] ----
#pragma unroll
    for (int it = 0; it < 2; it++) {
      int d0 = (tid & 15) * 8;
      int hp = (tid >> 4) + it * 16;  // kr pair index 0..31
      const unsigned short* v0 = (const unsigned short*)kvup +
          (size_t)(b * S_LEN + kb + 2 * hp) * (NH * 256) + h * 256 + 128 + d0;
      const unsigned short* v1 = v0 + NH * 256;
      us8 a = *(const us8*)v0;
      us8 bb = *(const us8*)v1;
#pragma unroll
      for (int z = 0; z < 8; z++)
        Vt2[(d0 + z) * 33 + hp] = (unsigned)a[z] | ((unsigned)bb[z] << 16);
    }
    __syncthreads();

    // ---- S^T = K·Q^T: rows kpos (m), cols q (n) ----
    f32x4 st[4];
#pragma unroll
    for (int mt = 0; mt < 4; mt++) {
      f32x4 acc = {0.f, 0.f, 0.f, 0.f};
#pragma unroll
      for (int kc = 0; kc < 6; kc++) {
        bf16x8 kf = *(const bf16x8*)&Ks[(mt * 16 + ml) * KS + kc * 32 + quad * 8];
        acc = __builtin_amdgcn_mfma_f32_16x16x32_bf16(kf, Qf[kc], acc, 0, 0, 0);
      }
      st[mt] = acc;
    }

    // ---- online softmax: lane owns q = qw+ml (replicated across quads) ----
    const int qg = qw + ml;
    float mloc = -1e30f;
#pragma unroll
    for (int mt = 0; mt < 4; mt++)
#pragma unroll
      for (int j = 0; j < 4; j++) {
        int kpos = kb + mt * 16 + quad * 4 + j;
        float s = st[mt][j] * scale;
        s = (kpos > qg) ? -1e30f : s;
        st[mt][j] = s;
        mloc = fmaxf(mloc, s);
      }
    mloc = fmaxf(mloc, __shfl_xor(mloc, 16, 64));
    mloc = fmaxf(mloc, __shfl_xor(mloc, 32, 64));
    float m_new = fmaxf(m_i, mloc);
    float alpha = __expf(m_i - m_new);
    float psum = 0.0f;
#pragma unroll
    for (int mt = 0; mt < 4; mt++)
#pragma unroll
      for (int j = 0; j < 4; j++) {
        float p = __expf(st[mt][j] - m_new);
        psum += p;
        myP[ml * PS + mt * 16 + quad * 4 + j] = f2bf(p);
      }
    psum += __shfl_xor(psum, 16, 64);
    psum += __shfl_xor(psum, 32, 64);
    l_i = l_i * alpha + psum;
    m_i = m_new;

    // rescale O: lane's O rows are q_local = quad*4+j -> fetch their alpha
    float aj[4];
#pragma unroll
    for (int j = 0; j < 4; j++) aj[j] = __shfl(alpha, quad * 4 + j, 64);
#pragma unroll
    for (int nt = 0; nt < 8; nt++)
#pragma unroll
      for (int j = 0; j < 4; j++) O[nt][j] *= aj[j];

    asm volatile("s_waitcnt lgkmcnt(0)" ::: "memory");  // P writes -> P reads

    // ---- PV: O[q][v] += P[q][kpos] · V^T[v][kpos] ----
#pragma unroll
    for (int kc = 0; kc < 2; kc++) {
      bf16x8 pf = *(const bf16x8*)&myP[ml * PS + kc * 32 + quad * 8];
#pragma unroll
      for (int nt = 0; nt < 8; nt++) {
        const unsigned* vp = &Vt2[(nt * 16 + ml) * 33 + kc * 16 + quad * 4];
        union { unsigned u[4]; bf16x8 v; } bv;
        bv.u[0] = vp[0]; bv.u[1] = vp[1]; bv.u[2] = vp[2]; bv.u[3] = vp[3];
        O[nt] = __builtin_amdgcn_mfma_f32_16x16x32_bf16(pf, bv.v, O[nt], 0, 0, 0);
      }
    }
  }

  // ---- epilogue: O row q_local = quad*4+j, col v = nt*16+ml ----
  float inv[4];
#pragma unroll
  for (int j = 0; j < 4; j++) inv[j] = 1.0f / __shfl(l_i, quad * 4 + j, 64);
#pragma unroll
  for (int j = 0; j < 4; j++) {
    size_t orow = (size_t)(b * S_LEN + qw + quad * 4 + j) * (NH * DV) + h * DV;
#pragma unroll
    for (int nt = 0; nt < 8; nt++)
      attn_out[orow + nt * 16 + ml] = __float2bfloat16(O[nt][j] * inv[j]);
  }
}

// ---------------- launch ----------------
extern "C" void kernel_launch(void* const* d_in, const int* in_sizes, int n_in,
                              void* d_out, int out_size, void* d_ws, size_t ws_size,
                              hipStream_t stream) {
  const float* x     = (const float*)d_in[0];
  const float* freqs = (const float*)d_in[2];
  const float* wq    = (const float*)d_in[4];
  const float* wkva  = (const float*)d_in[5];
  const float* wkvb  = (const float*)d_in[6];
  const float* wo    = (const float*)d_in[7];
  const float* kvnw  = (const float*)d_in[8];
  float* out = (float*)d_out;

  char* ws = (char*)d_ws;
  size_t off = 0;
  auto alloc = [&](size_t bytes) {
    void* p = ws + off;
    off += (bytes + 255) & ~(size_t)255;
    return p;
  };
  __hip_bfloat16* x_bf    = (__hip_bfloat16*)alloc((size_t)BS_TOT * 2048 * 2);
  __hip_bfloat16* wq_bf   = (__hip_bfloat16*)alloc((size_t)3072 * 2048 * 2);
  __hip_bfloat16* wkva_bf = (__hip_bfloat16*)alloc((size_t)576 * 2048 * 2);
  __hip_bfloat16* wkvb_bf = (__hip_bfloat16*)alloc((size_t)4096 * 512 * 2);
  __hip_bfloat16* wo_bf   = (__hip_bfloat16*)alloc((size_t)2048 * 2048 * 2);
  __hip_bfloat16* q_bf    = (__hip_bfloat16*)alloc((size_t)BS_TOT * 3072 * 2);
  float*          kva     = (float*)alloc((size_t)BS_TOT * 576 * 4);
  __hip_bfloat16* latent  = (__hip_bfloat16*)alloc((size_t)BS_TOT * 512 * 2);
  float*          kpe     = (float*)alloc((size_t)BS_TOT * 64 * 4);
  __hip_bfloat16* kvup    = (__hip_bfloat16*)alloc((size_t)BS_TOT * 4096 * 2);
  __hip_bfloat16* attn    = (__hip_bfloat16*)alloc((size_t)BS_TOT * 2048 * 2);

  cast_f32_bf16_kernel<<<2048, 256, 0, stream>>>(x, x_bf, BS_TOT * 2048);
  cast_f32_bf16_kernel<<<2048, 256, 0, stream>>>(wq, wq_bf, 3072 * 2048);
  cast_f32_bf16_kernel<<<1024, 256, 0, stream>>>(wkva, wkva_bf, 576 * 2048);
  cast_f32_bf16_kernel<<<1024, 256, 0, stream>>>(wkvb, wkvb_bf, 4096 * 512);
  cast_f32_bf16_kernel<<<2048, 256, 0, stream>>>(wo, wo_bf, 2048 * 2048);

  gemm_bt<1><<<dim3(3072 / 128, BS_TOT / 128), 256, 0, stream>>>(
      x_bf, wq_bf, q_bf, BS_TOT, 3072, 2048);
  rope_q_kernel<<<BS_TOT, 256, 0, stream>>>(q_bf, freqs);

  gemm_bt<0><<<dim3(5, BS_TOT / 128), 256, 0, stream>>>(
      x_bf, wkva_bf, kva, BS_TOT, 576, 2048);
  rms_rope_kv_kernel<<<BS_TOT, 256, 0, stream>>>(kva, kvnw, freqs, latent, kpe);

  gemm_bt<1><<<dim3(4096 / 128, BS_TOT / 128), 256, 0, stream>>>(
      latent, wkvb_bf, kvup, BS_TOT, 4096, 512);

  attn_mfma_kernel<<<dim3(S_LEN / 64, NH, 2), 256, 0, stream>>>(
      q_bf, kvup, kpe, attn);

  gemm_bt<0><<<dim3(2048 / 128, BS_TOT / 128), 256, 0, stream>>>(
      attn, wo_bf, out, BS_TOT, 2048, 2048);
}

// Round 3
// 571.437 us; speedup vs baseline: 6.7071x; 1.3717x over previous
//
#include <hip/hip_runtime.h>
#include <hip/hip_bf16.h>

// MLA prefill: B=2,S=2048,DIM=2048,NH=16,D_NOPE=128,D_ROPE=64,D_V=128,KV_RANK=512
// R3: pipelined MFMA flash attention — 512-thr/128-q blocks, register-relay
// prefetch of K/V, swizzled conflict-free V^T layout, dword-packed P.

typedef __bf16 bf16x8 __attribute__((ext_vector_type(8)));
typedef float  f32x4  __attribute__((ext_vector_type(4)));
typedef unsigned short us8 __attribute__((ext_vector_type(8)));

#define S_LEN   2048
#define BS_TOT  4096   // B*S
#define NH      16
#define DQK     192
#define DV      128
#define KV_RANK 512

__device__ inline unsigned short f2bf(float f) {
  __hip_bfloat16 h = __float2bfloat16(f);
  return *reinterpret_cast<unsigned short*>(&h);
}
__device__ inline unsigned int pack2bf(float a, float b) {
  return (unsigned int)f2bf(a) | ((unsigned int)f2bf(b) << 16);
}

// ---------------- f32 -> bf16 cast ----------------
__global__ void cast_f32_bf16_kernel(const float* __restrict__ src,
                                     __hip_bfloat16* __restrict__ dst, int n) {
  int tid = blockIdx.x * blockDim.x + threadIdx.x;
  int stride = gridDim.x * blockDim.x;
  for (int i = tid * 4; i < n; i += stride * 4) {
    f32x4 v = *(const f32x4*)(src + i);
    dst[i + 0] = __float2bfloat16(v.x);
    dst[i + 1] = __float2bfloat16(v.y);
    dst[i + 2] = __float2bfloat16(v.z);
    dst[i + 3] = __float2bfloat16(v.w);
  }
}

// ---------------- bf16 MFMA GEMM: C[M,N] = A[M,K] @ Bw[N,K]^T ----------------
template<int OUT_BF16>
__global__ __launch_bounds__(256) void gemm_bt(const __hip_bfloat16* __restrict__ A,
                                               const __hip_bfloat16* __restrict__ Bw,
                                               void* __restrict__ Cp,
                                               int M, int N, int K) {
  constexpr int BM = 128, BN = 128, BK = 32;
  __shared__ alignas(16) unsigned short As[BM * BK];
  __shared__ alignas(16) unsigned short Bs[BN * BK];
  const int tid  = threadIdx.x;
  const int m0   = blockIdx.y * BM, n0 = blockIdx.x * BN;
  const int w    = tid >> 6, lane = tid & 63;
  const int wm   = (w >> 1) * 64, wn = (w & 1) * 64;
  const int ml   = lane & 15, quad = lane >> 4;
  const int lrow = tid >> 2;
  const int lcol = (tid & 3) * 8;

  f32x4 acc[4][4];
#pragma unroll
  for (int i = 0; i < 4; i++)
#pragma unroll
    for (int j = 0; j < 4; j++)
#pragma unroll
      for (int e = 0; e < 4; e++) acc[i][j][e] = 0.0f;

  const unsigned short* Ag = (const unsigned short*)A;
  const unsigned short* Bg = (const unsigned short*)Bw;

  for (int k0 = 0; k0 < K; k0 += BK) {
    __syncthreads();
    *(us8*)&As[lrow * BK + lcol] =
        *(const us8*)&Ag[(size_t)(m0 + lrow) * K + k0 + lcol];
    *(us8*)&As[(lrow + 64) * BK + lcol] =
        *(const us8*)&Ag[(size_t)(m0 + lrow + 64) * K + k0 + lcol];
    int n1 = n0 + lrow, n2 = n0 + lrow + 64;
    us8 bv0, bv1;
#pragma unroll
    for (int z = 0; z < 8; z++) { bv0[z] = 0; bv1[z] = 0; }
    if (n1 < N) bv0 = *(const us8*)&Bg[(size_t)n1 * K + k0 + lcol];
    if (n2 < N) bv1 = *(const us8*)&Bg[(size_t)n2 * K + k0 + lcol];
    *(us8*)&Bs[lrow * BK + lcol] = bv0;
    *(us8*)&Bs[(lrow + 64) * BK + lcol] = bv1;
    __syncthreads();

    bf16x8 af[4], bfr[4];
#pragma unroll
    for (int mi = 0; mi < 4; mi++)
      af[mi] = *(const bf16x8*)&As[(wm + mi * 16 + ml) * BK + quad * 8];
#pragma unroll
    for (int ni = 0; ni < 4; ni++)
      bfr[ni] = *(const bf16x8*)&Bs[(wn + ni * 16 + ml) * BK + quad * 8];
#pragma unroll
    for (int mi = 0; mi < 4; mi++)
#pragma unroll
      for (int ni = 0; ni < 4; ni++)
        acc[mi][ni] = __builtin_amdgcn_mfma_f32_16x16x32_bf16(af[mi], bfr[ni],
                                                              acc[mi][ni], 0, 0, 0);
  }

#pragma unroll
  for (int mi = 0; mi < 4; mi++) {
#pragma unroll
    for (int ni = 0; ni < 4; ni++) {
      int col = n0 + wn + ni * 16 + ml;
      if (col < N) {
#pragma unroll
        for (int j = 0; j < 4; j++) {
          int row = m0 + wm + mi * 16 + quad * 4 + j;
          float v = acc[mi][ni][j];
          if (OUT_BF16)
            ((__hip_bfloat16*)Cp)[(size_t)row * N + col] = __float2bfloat16(v);
          else
            ((float*)Cp)[(size_t)row * N + col] = v;
        }
      }
    }
  }
}

// ---------------- RoPE on q_pe (in place, bf16 q [BS][NH*192]) ----------------
__global__ __launch_bounds__(256) void rope_q_kernel(__hip_bfloat16* __restrict__ q,
                                                     const float* __restrict__ freqs) {
  int si = blockIdx.x;
  int s  = si & (S_LEN - 1);
  int tid = threadIdx.x;
  for (int p = tid; p < NH * 32; p += 256) {
    int h = p >> 5, i = p & 31;
    size_t base = (size_t)si * (NH * DQK) + h * DQK + 128 + 2 * i;
    float c  = freqs[s * 64 + 2 * i];
    float sn = freqs[s * 64 + 2 * i + 1];
    float x0 = __bfloat162float(q[base]);
    float x1 = __bfloat162float(q[base + 1]);
    q[base]     = __float2bfloat16(x0 * c - x1 * sn);
    q[base + 1] = __float2bfloat16(x0 * sn + x1 * c);
  }
}

// -------- RMSNorm(kv latent) -> bf16, RoPE(k_pe) -> bf16 ---------------------
__global__ __launch_bounds__(256) void rms_rope_kv_kernel(
    const float* __restrict__ kva, const float* __restrict__ w,
    const float* __restrict__ freqs, __hip_bfloat16* __restrict__ latent,
    __hip_bfloat16* __restrict__ kpe_out) {
  int si = blockIdx.x;
  int tid = threadIdx.x;
  const float* row = kva + (size_t)si * 576;
  float v0 = row[tid], v1 = row[tid + 256];
  float ss = v0 * v0 + v1 * v1;
#pragma unroll
  for (int off = 1; off < 64; off <<= 1) ss += __shfl_xor(ss, off, 64);
  __shared__ float red[4];
  if ((tid & 63) == 0) red[tid >> 6] = ss;
  __syncthreads();
  float tot = red[0] + red[1] + red[2] + red[3];
  float r = rsqrtf(tot / 512.0f + 1e-6f);
  latent[(size_t)si * 512 + tid]       = __float2bfloat16(v0 * r * w[tid]);
  latent[(size_t)si * 512 + tid + 256] = __float2bfloat16(v1 * r * w[tid + 256]);
  if (tid < 32) {
    int s = si & (S_LEN - 1);
    float c  = freqs[s * 64 + 2 * tid];
    float sn = freqs[s * 64 + 2 * tid + 1];
    float x0 = row[512 + 2 * tid], x1 = row[512 + 2 * tid + 1];
    kpe_out[(size_t)si * 64 + 2 * tid]     = __float2bfloat16(x0 * c - x1 * sn);
    kpe_out[(size_t)si * 64 + 2 * tid + 1] = __float2bfloat16(x0 * sn + x1 * c);
  }
}

// ---------------- pipelined MFMA flash attention -------------------------------
// grid (S/128, NH, B) with reversed qt; 512 threads = 8 waves x 16 q.
// K-tile 64. Register-relay prefetch of next K/V tile overlaps compute.
// Ks: [64][200] bf16. Vt2: pair-packed V^T [d=0..127][hp=0..31] stride 36 dw,
// XOR-swizzled by (d>>3)&7 -> 2-way writes, conflict-free b128 reads.
// Ps: per-wave [16 q][32 k] bf16 as dwords, stride 36 dw.
__global__ __launch_bounds__(512, 4) void attn_mfma_kernel(
    const __hip_bfloat16* __restrict__ qb,    // [BS][NH*192]
    const __hip_bfloat16* __restrict__ kvup,  // [BS][NH*256] (nope|v per head)
    const __hip_bfloat16* __restrict__ kpe,   // [BS][64] bf16
    __hip_bfloat16* __restrict__ attn_out) {  // [BS][NH*128]
  constexpr int KS = 200;   // Ks row stride (bf16 elems)
  constexpr int VS = 36;    // Vt2 row stride (dwords)
  constexpr int PS = 36;    // Ps row stride (dwords)
  __shared__ alignas(16) unsigned short Ks[64 * KS];    // 25600 B
  __shared__ alignas(16) unsigned int   Vt2[128 * VS];  // 18432 B
  __shared__ alignas(16) unsigned int   Ps[8][16 * PS]; // 18432 B

  const int qt = (gridDim.x - 1) - blockIdx.x;  // big blocks first
  const int h = blockIdx.y, b = blockIdx.z;
  const int tid = threadIdx.x, wave = tid >> 6, lane = tid & 63;
  const int ml = lane & 15, quad = lane >> 4;
  const int qw = qt * 128 + wave * 16;
  const float scale = 0.07216878364870322f;  // 192^-0.5

  // resident Q B-frags: n=ml -> q row qw+ml; k = kc*32 + quad*8 + j
  bf16x8 Qf[6];
  {
    const unsigned short* qrow = (const unsigned short*)qb +
        (size_t)(b * S_LEN + qw + ml) * (NH * DQK) + h * DQK;
#pragma unroll
    for (int kc = 0; kc < 6; kc++)
      Qf[kc] = *(const bf16x8*)(qrow + kc * 32 + quad * 8);
  }

  // staging index precompute
  const int m16 = tid & 15;           // V: d-chunk owner
  const int hp  = tid >> 4;           // V: k-pair index 0..31
  const int vkey = (m16 & 7) << 2;    // V write swizzle
  const unsigned short* kvbase = (const unsigned short*)kvup;
  const unsigned short* kpbase = (const unsigned short*)kpe;

  float m_i = -1e30f, l_i = 0.0f;
  f32x4 O[8];
#pragma unroll
  for (int nt = 0; nt < 8; nt++)
#pragma unroll
    for (int j = 0; j < 4; j++) O[nt][j] = 0.0f;

  unsigned int* myP = Ps[wave];
  const int nkt = 2 * qt + 2;

  // ---- prefetch tile 0 into registers ----
  us8 Kpre[3], Vpre[2];
  {
    const int kb = 0;
#pragma unroll
    for (int it = 0; it < 3; it++) {
      int i = tid + it * 512;
      int r = i / 24, c = i - r * 24;
      size_t grow = (size_t)(b * S_LEN + kb + r);
      Kpre[it] = (c < 16)
          ? *(const us8*)(kvbase + grow * (NH * 256) + h * 256 + c * 8)
          : *(const us8*)(kpbase + grow * 64 + (c - 16) * 8);
    }
    const unsigned short* v0 = kvbase +
        (size_t)(b * S_LEN + kb + 2 * hp) * (NH * 256) + h * 256 + 128 + m16 * 8;
    Vpre[0] = *(const us8*)v0;
    Vpre[1] = *(const us8*)(v0 + NH * 256);
  }

  for (int kt = 0; kt < nkt; kt++) {
    const int kb = kt * 64;
    __syncthreads();  // all waves done reading previous tile
    // ---- write prefetched K ----
#pragma unroll
    for (int it = 0; it < 3; it++) {
      int i = tid + it * 512;
      int r = i / 24, c = i - r * 24;
      *(us8*)&Ks[r * KS + c * 8] = Kpre[it];
    }
    // ---- write prefetched V (pair-packed, swizzled) ----
#pragma unroll
    for (int z = 0; z < 8; z++) {
      int d = m16 * 8 + z;
      Vt2[d * VS + (hp ^ vkey)] =
          (unsigned)(unsigned short)Vpre[0][z] |
          ((unsigned)(unsigned short)Vpre[1][z] << 16);
    }
    __syncthreads();

    // ---- prefetch next tile ----
    if (kt + 1 < nkt) {
      const int kb2 = kb + 64;
#pragma unroll
      for (int it = 0; it < 3; it++) {
        int i = tid + it * 512;
        int r = i / 24, c = i - r * 24;
        size_t grow = (size_t)(b * S_LEN + kb2 + r);
        Kpre[it] = (c < 16)
            ? *(const us8*)(kvbase + grow * (NH * 256) + h * 256 + c * 8)
            : *(const us8*)(kpbase + grow * 64 + (c - 16) * 8);
      }
      const unsigned short* v0 = kvbase +
          (size_t)(b * S_LEN + kb2 + 2 * hp) * (NH * 256) + h * 256 + 128 + m16 * 8;
      Vpre[0] = *(const us8*)v0;
      Vpre[1] = *(const us8*)(v0 + NH * 256);
    }

    // ---- per-wave causal skip ----
    if (kb > qw + 15) continue;

    // ---- S^T = K·Q^T: rows kpos (m), cols q (n=ml) ----
    f32x4 st[4];
#pragma unroll
    for (int mt = 0; mt < 4; mt++) {
      f32x4 acc = {0.f, 0.f, 0.f, 0.f};
#pragma unroll
      for (int kc = 0; kc < 6; kc++) {
        bf16x8 kf = *(const bf16x8*)&Ks[(mt * 16 + ml) * KS + kc * 32 + quad * 8];
        acc = __builtin_amdgcn_mfma_f32_16x16x32_bf16(kf, Qf[kc], acc, 0, 0, 0);
      }
      st[mt] = acc;
    }

    // ---- online softmax: lane owns q = qw+ml (replicated across quads) ----
    const int qg = qw + ml;
    float mloc = -1e30f;
#pragma unroll
    for (int mt = 0; mt < 4; mt++)
#pragma unroll
      for (int j = 0; j < 4; j++) {
        int kpos = kb + mt * 16 + quad * 4 + j;
        float s = st[mt][j] * scale;
        s = (kpos > qg) ? -1e30f : s;
        st[mt][j] = s;
        mloc = fmaxf(mloc, s);
      }
    mloc = fmaxf(mloc, __shfl_xor(mloc, 16, 64));
    mloc = fmaxf(mloc, __shfl_xor(mloc, 32, 64));
    float m_new = fmaxf(m_i, mloc);
    float alpha = __expf(m_i - m_new);
    float psum = 0.0f;
#pragma unroll
    for (int mt = 0; mt < 4; mt++) {
      float p0 = __expf(st[mt][0] - m_new);
      float p1 = __expf(st[mt][1] - m_new);
      float p2 = __expf(st[mt][2] - m_new);
      float p3 = __expf(st[mt][3] - m_new);
      psum += (p0 + p1) + (p2 + p3);
      myP[ml * PS + mt * 8 + quad * 2 + 0] = pack2bf(p0, p1);
      myP[ml * PS + mt * 8 + quad * 2 + 1] = pack2bf(p2, p3);
    }
    psum += __shfl_xor(psum, 16, 64);
    psum += __shfl_xor(psum, 32, 64);
    l_i = l_i * alpha + psum;
    m_i = m_new;

    // rescale O: lane's O rows are q_local = quad*4+j -> fetch their alpha
    float aj[4];
#pragma unroll
    for (int j = 0; j < 4; j++) aj[j] = __shfl(alpha, quad * 4 + j, 64);
#pragma unroll
    for (int nt = 0; nt < 8; nt++)
#pragma unroll
      for (int j = 0; j < 4; j++) O[nt][j] *= aj[j];

    asm volatile("s_waitcnt lgkmcnt(0)" ::: "memory");  // P writes -> P reads

    // ---- PV: O[q][v] += P[q][kpos] · V^T[v][kpos] ----
#pragma unroll
    for (int kc = 0; kc < 2; kc++) {
      bf16x8 pf = *(const bf16x8*)&myP[ml * PS + kc * 16 + quad * 4];
#pragma unroll
      for (int nt = 0; nt < 8; nt++) {
        int vrow = nt * 16 + ml;
        const unsigned int* vp =
            &Vt2[vrow * VS + ((kc * 16 + quad * 4) ^ (((vrow >> 3) & 7) << 2))];
        bf16x8 bv = *(const bf16x8*)vp;
        O[nt] = __builtin_amdgcn_mfma_f32_16x16x32_bf16(pf, bv, O[nt], 0, 0, 0);
      }
    }
  }

  // ---- epilogue: O row q_local = quad*4+j, col v = nt*16+ml ----
  float inv[4];
#pragma unroll
  for (int j = 0; j < 4; j++) inv[j] = 1.0f / __shfl(l_i, quad * 4 + j, 64);
#pragma unroll
  for (int j = 0; j < 4; j++) {
    size_t orow = (size_t)(b * S_LEN + qw + quad * 4 + j) * (NH * DV) + h * DV;
#pragma unroll
    for (int nt = 0; nt < 8; nt++)
      attn_out[orow + nt * 16 + ml] = __float2bfloat16(O[nt][j] * inv[j]);
  }
}

// ---------------- launch ----------------
extern "C" void kernel_launch(void* const* d_in, const int* in_sizes, int n_in,
                              void* d_out, int out_size, void* d_ws, size_t ws_size,
                              hipStream_t stream) {
  const float* x     = (const float*)d_in[0];
  const float* freqs = (const float*)d_in[2];
  const float* wq    = (const float*)d_in[4];
  const float* wkva  = (const float*)d_in[5];
  const float* wkvb  = (const float*)d_in[6];
  const float* wo    = (const float*)d_in[7];
  const float* kvnw  = (const float*)d_in[8];
  float* out = (float*)d_out;

  char* ws = (char*)d_ws;
  size_t off = 0;
  auto alloc = [&](size_t bytes) {
    void* p = ws + off;
    off += (bytes + 255) & ~(size_t)255;
    return p;
  };
  __hip_bfloat16* x_bf    = (__hip_bfloat16*)alloc((size_t)BS_TOT * 2048 * 2);
  __hip_bfloat16* wq_bf   = (__hip_bfloat16*)alloc((size_t)3072 * 2048 * 2);
  __hip_bfloat16* wkva_bf = (__hip_bfloat16*)alloc((size_t)576 * 2048 * 2);
  __hip_bfloat16* wkvb_bf = (__hip_bfloat16*)alloc((size_t)4096 * 512 * 2);
  __hip_bfloat16* wo_bf   = (__hip_bfloat16*)alloc((size_t)2048 * 2048 * 2);
  __hip_bfloat16* q_bf    = (__hip_bfloat16*)alloc((size_t)BS_TOT * 3072 * 2);
  float*          kva     = (float*)alloc((size_t)BS_TOT * 576 * 4);
  __hip_bfloat16* latent  = (__hip_bfloat16*)alloc((size_t)BS_TOT * 512 * 2);
  __hip_bfloat16* kpe     = (__hip_bfloat16*)alloc((size_t)BS_TOT * 64 * 2);
  __hip_bfloat16* kvup    = (__hip_bfloat16*)alloc((size_t)BS_TOT * 4096 * 2);
  __hip_bfloat16* attn    = (__hip_bfloat16*)alloc((size_t)BS_TOT * 2048 * 2);

  cast_f32_bf16_kernel<<<2048, 256, 0, stream>>>(x, x_bf, BS_TOT * 2048);
  cast_f32_bf16_kernel<<<2048, 256, 0, stream>>>(wq, wq_bf, 3072 * 2048);
  cast_f32_bf16_kernel<<<1024, 256, 0, stream>>>(wkva, wkva_bf, 576 * 2048);
  cast_f32_bf16_kernel<<<1024, 256, 0, stream>>>(wkvb, wkvb_bf, 4096 * 512);
  cast_f32_bf16_kernel<<<2048, 256, 0, stream>>>(wo, wo_bf, 2048 * 2048);

  gemm_bt<1><<<dim3(3072 / 128, BS_TOT / 128), 256, 0, stream>>>(
      x_bf, wq_bf, q_bf, BS_TOT, 3072, 2048);
  rope_q_kernel<<<BS_TOT, 256, 0, stream>>>(q_bf, freqs);

  gemm_bt<0><<<dim3(5, BS_TOT / 128), 256, 0, stream>>>(
      x_bf, wkva_bf, kva, BS_TOT, 576, 2048);
  rms_rope_kv_kernel<<<BS_TOT, 256, 0, stream>>>(kva, kvnw, freqs, latent, kpe);

  gemm_bt<1><<<dim3(4096 / 128, BS_TOT / 128), 256, 0, stream>>>(
      latent, wkvb_bf, kvup, BS_TOT, 4096, 512);

  attn_mfma_kernel<<<dim3(S_LEN / 128, NH, 2), 512, 0, stream>>>(
      q_bf, kvup, kpe, attn);

  gemm_bt<0><<<dim3(2048 / 128, BS_TOT / 128), 256, 0, stream>>>(
      attn, wo_bf, out, BS_TOT, 2048, 2048);
}

// Round 5
// 561.148 us; speedup vs baseline: 6.8301x; 1.0183x over previous
//
#include <hip/hip_runtime.h>
#include <hip/hip_bf16.h>

// MLA prefill: B=2,S=2048,DIM=2048,NH=16,D_NOPE=128,D_ROPE=64,D_V=128,KV_RANK=512
// R5: R4 with the Ps stride bug fixed (PS 20 -> 36; a P row is 64 bf16 = 32
// dwords, PS=20 made rows overlap + overflow into the next wave's region).
// GEMMs: global_load_lds width-16 (m97). Attention: O^T=V^T·P^T swap,
// exp2-domain softmax, register-relay prefetch.

typedef __bf16 bf16x8 __attribute__((ext_vector_type(8)));
typedef float  f32x4  __attribute__((ext_vector_type(4)));
typedef unsigned short us8 __attribute__((ext_vector_type(8)));
typedef unsigned short us4 __attribute__((ext_vector_type(4)));

#define S_LEN   2048
#define BS_TOT  4096   // B*S
#define NH      16
#define DQK     192
#define DV      128
#define KV_RANK 512

__device__ inline unsigned short f2bf(float f) {
  __hip_bfloat16 h = __float2bfloat16(f);
  return *reinterpret_cast<unsigned short*>(&h);
}
__device__ inline unsigned int pack2bf(float a, float b) {
  return (unsigned int)f2bf(a) | ((unsigned int)f2bf(b) << 16);
}
__device__ inline void glds16(const void* g, void* l) {
  __builtin_amdgcn_global_load_lds(
      (const __attribute__((address_space(1))) unsigned int*)g,
      (__attribute__((address_space(3))) unsigned int*)l, 16, 0, 0);
}

// ---------------- f32 -> bf16 cast (with zero pad to npad) ----------------
__global__ void cast_f32_bf16_kernel(const float* __restrict__ src,
                                     __hip_bfloat16* __restrict__ dst,
                                     int n, int npad) {
  int tid = blockIdx.x * blockDim.x + threadIdx.x;
  int stride = gridDim.x * blockDim.x;
  for (int i = tid * 4; i < npad; i += stride * 4) {
    if (i < n) {
      f32x4 v = *(const f32x4*)(src + i);
      dst[i + 0] = __float2bfloat16(v.x);
      dst[i + 1] = __float2bfloat16(v.y);
      dst[i + 2] = __float2bfloat16(v.z);
      dst[i + 3] = __float2bfloat16(v.w);
    } else {
      dst[i + 0] = __float2bfloat16(0.f);
      dst[i + 1] = __float2bfloat16(0.f);
      dst[i + 2] = __float2bfloat16(0.f);
      dst[i + 3] = __float2bfloat16(0.f);
    }
  }
}

// ---------------- bf16 MFMA GEMM: C[M,N] = A[M,K] @ Bw[N,K]^T ----------------
// m97 structure: global_load_lds width-16 staging, 128x128 tile, BK=32.
// Bw must have >= ceil(N/128)*128 valid rows (zero-padded if needed).
template<int OUT_BF16>
__global__ __launch_bounds__(256) void gemm_bt(const __hip_bfloat16* __restrict__ A,
                                               const __hip_bfloat16* __restrict__ Bw,
                                               void* __restrict__ Cp,
                                               int M, int N, int K) {
  constexpr int BM = 128, BN = 128, BK = 32;
  __shared__ alignas(16) unsigned short As[BM * BK];
  __shared__ alignas(16) unsigned short Bs[BN * BK];
  const int tid  = threadIdx.x;
  const int m0   = blockIdx.y * BM, n0 = blockIdx.x * BN;
  const int w    = tid >> 6, lane = tid & 63;
  const int wm   = (w >> 1) * 64, wn = (w & 1) * 64;
  const int ml   = lane & 15, quad = lane >> 4;
  const int srow = w * 16 + (lane >> 2);   // staging row within 64-row half
  const int scol = (lane & 3) * 8;         // staging col (elems)

  f32x4 acc[4][4];
#pragma unroll
  for (int i = 0; i < 4; i++)
#pragma unroll
    for (int j = 0; j < 4; j++)
#pragma unroll
      for (int e = 0; e < 4; e++) acc[i][j][e] = 0.0f;

  const unsigned short* Ag = (const unsigned short*)A;
  const unsigned short* Bg = (const unsigned short*)Bw;
  const unsigned short* a0 = Ag + (size_t)(m0 + srow) * K + scol;
  const unsigned short* a1 = Ag + (size_t)(m0 + srow + 64) * K + scol;
  const unsigned short* b0 = Bg + (size_t)(n0 + srow) * K + scol;
  const unsigned short* b1 = Bg + (size_t)(n0 + srow + 64) * K + scol;
  unsigned short* lA0 = &As[(w * 16) * BK];        // wave-uniform LDS bases
  unsigned short* lA1 = &As[(64 + w * 16) * BK];
  unsigned short* lB0 = &Bs[(w * 16) * BK];
  unsigned short* lB1 = &Bs[(64 + w * 16) * BK];

  for (int k0 = 0; k0 < K; k0 += BK) {
    __syncthreads();
    glds16(a0 + k0, lA0);
    glds16(a1 + k0, lA1);
    glds16(b0 + k0, lB0);
    glds16(b1 + k0, lB1);
    __syncthreads();

    bf16x8 af[4], bfr[4];
#pragma unroll
    for (int mi = 0; mi < 4; mi++)
      af[mi] = *(const bf16x8*)&As[(wm + mi * 16 + ml) * BK + quad * 8];
#pragma unroll
    for (int ni = 0; ni < 4; ni++)
      bfr[ni] = *(const bf16x8*)&Bs[(wn + ni * 16 + ml) * BK + quad * 8];
#pragma unroll
    for (int mi = 0; mi < 4; mi++)
#pragma unroll
      for (int ni = 0; ni < 4; ni++)
        acc[mi][ni] = __builtin_amdgcn_mfma_f32_16x16x32_bf16(af[mi], bfr[ni],
                                                              acc[mi][ni], 0, 0, 0);
  }

#pragma unroll
  for (int mi = 0; mi < 4; mi++) {
#pragma unroll
    for (int ni = 0; ni < 4; ni++) {
      int col = n0 + wn + ni * 16 + ml;
      if (col < N) {
#pragma unroll
        for (int j = 0; j < 4; j++) {
          int row = m0 + wm + mi * 16 + quad * 4 + j;
          float v = acc[mi][ni][j];
          if (OUT_BF16)
            ((__hip_bfloat16*)Cp)[(size_t)row * N + col] = __float2bfloat16(v);
          else
            ((float*)Cp)[(size_t)row * N + col] = v;
        }
      }
    }
  }
}

// ---------------- RoPE on q_pe (in place, bf16 q [BS][NH*192]) ----------------
__global__ __launch_bounds__(256) void rope_q_kernel(__hip_bfloat16* __restrict__ q,
                                                     const float* __restrict__ freqs) {
  int si = blockIdx.x;
  int s  = si & (S_LEN - 1);
  int tid = threadIdx.x;
  for (int p = tid; p < NH * 32; p += 256) {
    int h = p >> 5, i = p & 31;
    size_t base = (size_t)si * (NH * DQK) + h * DQK + 128 + 2 * i;
    float c  = freqs[s * 64 + 2 * i];
    float sn = freqs[s * 64 + 2 * i + 1];
    float x0 = __bfloat162float(q[base]);
    float x1 = __bfloat162float(q[base + 1]);
    q[base]     = __float2bfloat16(x0 * c - x1 * sn);
    q[base + 1] = __float2bfloat16(x0 * sn + x1 * c);
  }
}

// -------- RMSNorm(kv latent) -> bf16, RoPE(k_pe) -> bf16 ---------------------
__global__ __launch_bounds__(256) void rms_rope_kv_kernel(
    const float* __restrict__ kva, const float* __restrict__ w,
    const float* __restrict__ freqs, __hip_bfloat16* __restrict__ latent,
    __hip_bfloat16* __restrict__ kpe_out) {
  int si = blockIdx.x;
  int tid = threadIdx.x;
  const float* row = kva + (size_t)si * 576;
  float v0 = row[tid], v1 = row[tid + 256];
  float ss = v0 * v0 + v1 * v1;
#pragma unroll
  for (int off = 1; off < 64; off <<= 1) ss += __shfl_xor(ss, off, 64);
  __shared__ float red[4];
  if ((tid & 63) == 0) red[tid >> 6] = ss;
  __syncthreads();
  float tot = red[0] + red[1] + red[2] + red[3];
  float r = rsqrtf(tot / 512.0f + 1e-6f);
  latent[(size_t)si * 512 + tid]       = __float2bfloat16(v0 * r * w[tid]);
  latent[(size_t)si * 512 + tid + 256] = __float2bfloat16(v1 * r * w[tid + 256]);
  if (tid < 32) {
    int s = si & (S_LEN - 1);
    float c  = freqs[s * 64 + 2 * tid];
    float sn = freqs[s * 64 + 2 * tid + 1];
    float x0 = row[512 + 2 * tid], x1 = row[512 + 2 * tid + 1];
    kpe_out[(size_t)si * 64 + 2 * tid]     = __float2bfloat16(x0 * c - x1 * sn);
    kpe_out[(size_t)si * 64 + 2 * tid + 1] = __float2bfloat16(x0 * sn + x1 * c);
  }
}

// ---------------- pipelined MFMA flash attention -------------------------------
// grid (S/128, NH, B) reversed; 512 threads = 8 waves x 16 q. K-tile 64.
// S^T = K·Q^T (q on col=ml); PV as O^T = V^T·P^T (operand swap) so softmax
// state stays lane-local. exp2-domain softmax. Register-relay K/V prefetch.
__global__ __launch_bounds__(512, 4) void attn_mfma_kernel(
    const __hip_bfloat16* __restrict__ qb,    // [BS][NH*192]
    const __hip_bfloat16* __restrict__ kvup,  // [BS][NH*256] (nope|v per head)
    const __hip_bfloat16* __restrict__ kpe,   // [BS][64] bf16
    __hip_bfloat16* __restrict__ attn_out) {  // [BS][NH*128]
  constexpr int KS = 200;   // Ks row stride (bf16 elems)
  constexpr int VS = 36;    // Vt2 row stride (dwords)
  constexpr int PS = 36;    // Ps row stride (dwords) — row = 32 dw of data!
  __shared__ alignas(16) unsigned short Ks[64 * KS];    // 25600 B
  __shared__ alignas(16) unsigned int   Vt2[128 * VS];  // 18432 B
  __shared__ alignas(16) unsigned int   Ps[8][16 * PS]; // 18432 B

  const int qt = (gridDim.x - 1) - blockIdx.x;  // big blocks first
  const int h = blockIdx.y, b = blockIdx.z;
  const int tid = threadIdx.x, wave = tid >> 6, lane = tid & 63;
  const int ml = lane & 15, quad = lane >> 4;
  const int qw = qt * 128 + wave * 16;
  const float qs2 = 0.07216878364870322f * 1.4426950408889634f;  // scale*log2e

  // resident Q B-frags: n=ml -> q row qw+ml; k = kc*32 + quad*8 + j
  bf16x8 Qf[6];
  {
    const unsigned short* qrow = (const unsigned short*)qb +
        (size_t)(b * S_LEN + qw + ml) * (NH * DQK) + h * DQK;
#pragma unroll
    for (int kc = 0; kc < 6; kc++)
      Qf[kc] = *(const bf16x8*)(qrow + kc * 32 + quad * 8);
  }

  const int m16 = tid & 15;           // V: d-chunk owner
  const int hp  = tid >> 4;           // V: k-pair index 0..31
  const int vkey = (m16 & 7) << 2;    // V write swizzle
  const unsigned short* kvbase = (const unsigned short*)kvup;
  const unsigned short* kpbase = (const unsigned short*)kpe;

  float m_i = -1e30f, l_i = 0.0f;
  f32x4 O[8];  // O^T: reg j of tile nt = v=nt*16+quad*4+j, q=ml
#pragma unroll
  for (int nt = 0; nt < 8; nt++)
#pragma unroll
    for (int j = 0; j < 4; j++) O[nt][j] = 0.0f;

  unsigned int* myP = Ps[wave];
  const int nkt = 2 * qt + 2;

  // ---- prefetch tile 0 into registers ----
  us8 Kpre[3], Vpre[2];
  {
#pragma unroll
    for (int it = 0; it < 3; it++) {
      int i = tid + it * 512;
      int r = i / 24, c = i - r * 24;
      size_t grow = (size_t)(b * S_LEN + r);
      Kpre[it] = (c < 16)
          ? *(const us8*)(kvbase + grow * (NH * 256) + h * 256 + c * 8)
          : *(const us8*)(kpbase + grow * 64 + (c - 16) * 8);
    }
    const unsigned short* v0 = kvbase +
        (size_t)(b * S_LEN + 2 * hp) * (NH * 256) + h * 256 + 128 + m16 * 8;
    Vpre[0] = *(const us8*)v0;
    Vpre[1] = *(const us8*)(v0 + NH * 256);
  }

  for (int kt = 0; kt < nkt; kt++) {
    const int kb = kt * 64;
    __syncthreads();  // all waves done reading previous tile
#pragma unroll
    for (int it = 0; it < 3; it++) {
      int i = tid + it * 512;
      int r = i / 24, c = i - r * 24;
      *(us8*)&Ks[r * KS + c * 8] = Kpre[it];
    }
#pragma unroll
    for (int z = 0; z < 8; z++) {
      int d = m16 * 8 + z;
      Vt2[d * VS + (hp ^ vkey)] =
          (unsigned)(unsigned short)Vpre[0][z] |
          ((unsigned)(unsigned short)Vpre[1][z] << 16);
    }
    __syncthreads();

    if (kt + 1 < nkt) {
      const int kb2 = kb + 64;
#pragma unroll
      for (int it = 0; it < 3; it++) {
        int i = tid + it * 512;
        int r = i / 24, c = i - r * 24;
        size_t grow = (size_t)(b * S_LEN + kb2 + r);
        Kpre[it] = (c < 16)
            ? *(const us8*)(kvbase + grow * (NH * 256) + h * 256 + c * 8)
            : *(const us8*)(kpbase + grow * 64 + (c - 16) * 8);
      }
      const unsigned short* v0 = kvbase +
          (size_t)(b * S_LEN + kb2 + 2 * hp) * (NH * 256) + h * 256 + 128 + m16 * 8;
      Vpre[0] = *(const us8*)v0;
      Vpre[1] = *(const us8*)(v0 + NH * 256);
    }

    if (kb > qw + 15) continue;  // per-wave causal skip

    // ---- S^T = K·Q^T: rows kpos (m), cols q (n=ml) ----
    f32x4 st[4];
#pragma unroll
    for (int mt = 0; mt < 4; mt++) {
      f32x4 acc = {0.f, 0.f, 0.f, 0.f};
#pragma unroll
      for (int kc = 0; kc < 6; kc++) {
        bf16x8 kf = *(const bf16x8*)&Ks[(mt * 16 + ml) * KS + kc * 32 + quad * 8];
        acc = __builtin_amdgcn_mfma_f32_16x16x32_bf16(kf, Qf[kc], acc, 0, 0, 0);
      }
      st[mt] = acc;
    }

    // ---- online softmax in exp2 domain: lane owns q = qw+ml ----
    const int qg = qw + ml;
    float mloc = -1e30f;
#pragma unroll
    for (int mt = 0; mt < 4; mt++)
#pragma unroll
      for (int j = 0; j < 4; j++) {
        int kpos = kb + mt * 16 + quad * 4 + j;
        float s = st[mt][j] * qs2;
        s = (kpos > qg) ? -1e30f : s;
        st[mt][j] = s;
        mloc = fmaxf(mloc, s);
      }
    mloc = fmaxf(mloc, __shfl_xor(mloc, 16, 64));
    mloc = fmaxf(mloc, __shfl_xor(mloc, 32, 64));
    float m_new = fmaxf(m_i, mloc);
    float alpha = exp2f(m_i - m_new);
    float psum = 0.0f;
#pragma unroll
    for (int mt = 0; mt < 4; mt++) {
      float p0 = exp2f(st[mt][0] - m_new);
      float p1 = exp2f(st[mt][1] - m_new);
      float p2 = exp2f(st[mt][2] - m_new);
      float p3 = exp2f(st[mt][3] - m_new);
      psum += (p0 + p1) + (p2 + p3);
      myP[ml * PS + mt * 8 + quad * 2 + 0] = pack2bf(p0, p1);
      myP[ml * PS + mt * 8 + quad * 2 + 1] = pack2bf(p2, p3);
    }
    psum += __shfl_xor(psum, 16, 64);
    psum += __shfl_xor(psum, 32, 64);
    l_i = l_i * alpha + psum;
    m_i = m_new;

    // rescale O^T: all regs have q=ml -> lane-local alpha
#pragma unroll
    for (int nt = 0; nt < 8; nt++)
#pragma unroll
      for (int j = 0; j < 4; j++) O[nt][j] *= alpha;

    asm volatile("s_waitcnt lgkmcnt(0)" ::: "memory");  // P writes -> P reads

    // ---- PV as O^T = V^T·P^T: A=V^T rows (v,k), B=P rows (q,k) ----
#pragma unroll
    for (int kc = 0; kc < 2; kc++) {
      bf16x8 pf = *(const bf16x8*)&myP[ml * PS + kc * 16 + quad * 4];
#pragma unroll
      for (int nt = 0; nt < 8; nt++) {
        int vrow = nt * 16 + ml;
        const unsigned int* vp =
            &Vt2[vrow * VS + ((kc * 16 + quad * 4) ^ (((vrow >> 3) & 7) << 2))];
        bf16x8 bv = *(const bf16x8*)vp;
        O[nt] = __builtin_amdgcn_mfma_f32_16x16x32_bf16(bv, pf, O[nt], 0, 0, 0);
      }
    }
  }

  // ---- epilogue: O^T[v=nt*16+quad*4+j][q=ml]; lane-local 1/l ----
  float invl = 1.0f / l_i;
  size_t orow = (size_t)(b * S_LEN + qw + ml) * (NH * DV) + h * DV;
#pragma unroll
  for (int nt = 0; nt < 8; nt++) {
    us4 pk;
#pragma unroll
    for (int j = 0; j < 4; j++) pk[j] = f2bf(O[nt][j] * invl);
    *(us4*)((unsigned short*)attn_out + orow + nt * 16 + quad * 4) = pk;
  }
}

// ---------------- launch ----------------
extern "C" void kernel_launch(void* const* d_in, const int* in_sizes, int n_in,
                              void* d_out, int out_size, void* d_ws, size_t ws_size,
                              hipStream_t stream) {
  const float* x     = (const float*)d_in[0];
  const float* freqs = (const float*)d_in[2];
  const float* wq    = (const float*)d_in[4];
  const float* wkva  = (const float*)d_in[5];
  const float* wkvb  = (const float*)d_in[6];
  const float* wo    = (const float*)d_in[7];
  const float* kvnw  = (const float*)d_in[8];
  float* out = (float*)d_out;

  char* ws = (char*)d_ws;
  size_t off = 0;
  auto alloc = [&](size_t bytes) {
    void* p = ws + off;
    off += (bytes + 255) & ~(size_t)255;
    return p;
  };
  __hip_bfloat16* x_bf    = (__hip_bfloat16*)alloc((size_t)BS_TOT * 2048 * 2);
  __hip_bfloat16* wq_bf   = (__hip_bfloat16*)alloc((size_t)3072 * 2048 * 2);
  __hip_bfloat16* wkva_bf = (__hip_bfloat16*)alloc((size_t)640 * 2048 * 2);  // padded
  __hip_bfloat16* wkvb_bf = (__hip_bfloat16*)alloc((size_t)4096 * 512 * 2);
  __hip_bfloat16* wo_bf   = (__hip_bfloat16*)alloc((size_t)2048 * 2048 * 2);
  __hip_bfloat16* q_bf    = (__hip_bfloat16*)alloc((size_t)BS_TOT * 3072 * 2);
  float*          kva     = (float*)alloc((size_t)BS_TOT * 576 * 4);
  __hip_bfloat16* latent  = (__hip_bfloat16*)alloc((size_t)BS_TOT * 512 * 2);
  __hip_bfloat16* kpe     = (__hip_bfloat16*)alloc((size_t)BS_TOT * 64 * 2);
  __hip_bfloat16* kvup    = (__hip_bfloat16*)alloc((size_t)BS_TOT * 4096 * 2);
  __hip_bfloat16* attn    = (__hip_bfloat16*)alloc((size_t)BS_TOT * 2048 * 2);

  cast_f32_bf16_kernel<<<2048, 256, 0, stream>>>(x, x_bf, BS_TOT * 2048,
                                                 BS_TOT * 2048);
  cast_f32_bf16_kernel<<<2048, 256, 0, stream>>>(wq, wq_bf, 3072 * 2048,
                                                 3072 * 2048);
  cast_f32_bf16_kernel<<<1024, 256, 0, stream>>>(wkva, wkva_bf, 576 * 2048,
                                                 640 * 2048);
  cast_f32_bf16_kernel<<<1024, 256, 0, stream>>>(wkvb, wkvb_bf, 4096 * 512,
                                                 4096 * 512);
  cast_f32_bf16_kernel<<<2048, 256, 0, stream>>>(wo, wo_bf, 2048 * 2048,
                                                 2048 * 2048);

  gemm_bt<1><<<dim3(3072 / 128, BS_TOT / 128), 256, 0, stream>>>(
      x_bf, wq_bf, q_bf, BS_TOT, 3072, 2048);
  rope_q_kernel<<<BS_TOT, 256, 0, stream>>>(q_bf, freqs);

  gemm_bt<0><<<dim3(5, BS_TOT / 128), 256, 0, stream>>>(
      x_bf, wkva_bf, kva, BS_TOT, 576, 2048);
  rms_rope_kv_kernel<<<BS_TOT, 256, 0, stream>>>(kva, kvnw, freqs, latent, kpe);

  gemm_bt<1><<<dim3(4096 / 128, BS_TOT / 128), 256, 0, stream>>>(
      latent, wkvb_bf, kvup, BS_TOT, 4096, 512);

  attn_mfma_kernel<<<dim3(S_LEN / 128, NH, 2), 512, 0, stream>>>(
      q_bf, kvup, kpe, attn);

  gemm_bt<0><<<dim3(2048 / 128, BS_TOT / 128), 256, 0, stream>>>(
      attn, wo_bf, out, BS_TOT, 2048, 2048);
}